// Round 7
// baseline (190.119 us; speedup 1.0000x reference)
//
#include <hip/hip_runtime.h>
#include <hip/hip_bf16.h>
#include <stdint.h>

// PSM cosine cost volume, MI355X (gfx950).
// out[b,d,h,w] = (1/C) * sum_c L[b,c,h,w] * R[b,c,h,w-d],  0 where w<d.
// Banded Gram matrix via bf16 MFMA 16x16x32.
//
// R7: 256-thread blocks (4 waves), quarter-row (QW=80) per block -> 4
// independent barrier teams per CU (vs 2 of 8 waves): finer phase
// interleaving, less lockstep. Pipeline structure = R6 (register prefetch one
// chunk deep + lgkmcnt-only barriers; never drain vmcnt in the main loop).
// NOTE (measured R5/R6): __launch_bounds__ 2nd arg acts as min-BLOCKS-per-CU
// on this compiler ((512,4) capped VGPR at 64 and spilled; (512,2) -> 128).
// (256,4) -> 16 waves/CU -> 128-VGPR cap, prefetch (~56) fits.
//
// LDS layout per row lw (128B = 64 bf16 = KC channels), 16B slot s holds
// c in [8s',8s'+8) where s = s' ^ (lw&7) ^ ((lw>>4)&7):
//   (lw&7): read-side spread; ((lw>>4)&7): write-side spread, wave-uniform at
//   read (tile index) so fragment reads stay single ds_read_b128.
// Dword within slot = c-pair index (rp&3); bf16 pair = (even c, odd c).

#define B_ 4
#define C_ 512
#define H_ 96
#define W_ 312
#define D_ 48
#define HW_ (H_ * W_)      // 29952
#define CHW_ (C_ * HW_)

#define KC 64              // staged c per chunk
#define NCHUNK (C_ / KC)   // 8
#define NQ 4               // quarters per row
#define QW 80              // quarter width (last covers w=240..311, guarded)
#define LCOLS 80           // 5 N-tiles of 16
#define RCOLS 128          // [wq-48, wq+80): 8 M-tiles of 16 (pow2!)
#define PITCH 128          // LDS row pitch bytes (64 bf16 = KC)
#define LBYTES (LCOLS * PITCH)          // 10240
#define RBYTES (RCOLS * PITCH)          // 16384
#define SMEM_BYTES (LBYTES + RBYTES)    // 26624 -> 4+ blocks/CU by LDS

#define THREADS 256
#define LITEMS 3           // ceil(32*20 / 256): it=2 only tid<128 (wave-uniform)
#define RITEMS 4           // 32*32 / 256 exactly

typedef __bf16 bf16x8 __attribute__((ext_vector_type(8)));
typedef float  f32x4  __attribute__((ext_vector_type(4)));

__device__ __forceinline__ uint32_t pack2_bf16(float a, float b) {
    // RNE f32 -> bf16 pair (a = low half = even c)
    uint32_t ua = __builtin_bit_cast(uint32_t, a);
    uint32_t ub = __builtin_bit_cast(uint32_t, b);
    ua += 0x7FFFu + ((ua >> 16) & 1u);
    ub += 0x7FFFu + ((ub >> 16) & 1u);
    return (ua >> 16) | (ub & 0xFFFF0000u);
}

// Byte offset of the 16B slot holding c-range [8*chi, 8*chi+8) of row lw.
__device__ __forceinline__ int lds_slotoff(int lw, int chi) {
    return lw * PITCH + ((chi ^ (lw & 7) ^ ((lw >> 4) & 7)) << 4);
}

// LDS-only drain + barrier (keeps global loads in flight across the barrier).
__device__ __forceinline__ void lds_barrier() {
    asm volatile("s_waitcnt lgkmcnt(0)" ::: "memory");
    __builtin_amdgcn_s_barrier();
}

__global__ __launch_bounds__(THREADS, 4)
void psm_cost_volume(const float* __restrict__ lf,
                     const float* __restrict__ rf,
                     float* __restrict__ out) {
    const int wq   = blockIdx.x * QW;   // 0,80,160,240
    const int h    = blockIdx.y;
    const int b    = blockIdx.z;
    const int tid  = threadIdx.x;
    const int lane = tid & 63;
    const int wave = tid >> 6;          // 4 waves
    const int l15  = lane & 15;
    const int l4   = lane >> 4;
    const int jj   = wave;              // A-tile offset 0..3

    extern __shared__ char smem[];
    // [0, LBYTES): L rows lw=0..79   (w  = wq + lw)
    // [LBYTES, +RBYTES): R rows lw=0..127 (w' = wq - 48 + lw)
    // epilogue reuses [0, D_*QW*4 = 15360) as f32 out staging

    const float* lbase = lf + (size_t)b * CHW_ + (size_t)h * W_;
    const float* rbase = rf + (size_t)b * CHW_ + (size_t)h * W_;

    f32x4 acc[5];
    #pragma unroll
    for (int i = 0; i < 5; ++i) acc[i] = f32x4{0.f, 0.f, 0.f, 0.f};

    // prefetch registers, one chunk deep: (3+4) items x 2 loads = 56 VGPR
    f32x4 pl0[LITEMS], pl1[LITEMS], pr0[RITEMS], pr1[RITEMS];

    // ---- issue loads for chunk starting at channel c0 into prefetch regs ----
    auto LOADS = [&](int c0) {
        #pragma unroll
        for (int it = 0; it < LITEMS; ++it) {
            int idx = tid + it * THREADS;        // q-fastest: coalesced runs
            if (idx < 32 * 20) {                 // it=2: tid<128, wave-uniform
                int rp = idx / 20;               // c-pair 0..31 (magic-mul)
                int q  = idx - rp * 20;          // float4 column 0..19
                int w4 = wq + 4 * q;
                pl0[it] = f32x4{0.f, 0.f, 0.f, 0.f};
                pl1[it] = f32x4{0.f, 0.f, 0.f, 0.f};
                if (w4 + 3 < W_) {               // quarter3 q>=18 OOB -> zeros
                    const float* g = lbase + (size_t)(c0 + 2 * rp) * HW_ + w4;
                    pl0[it] = *(const f32x4*)g;
                    pl1[it] = *(const f32x4*)(g + HW_);
                }
            }
        }
        #pragma unroll
        for (int it = 0; it < RITEMS; ++it) {
            int idx = tid + it * THREADS;
            int rp  = idx >> 5;                  // c-pair 0..31
            int q   = idx & 31;                  // float4 column 0..31
            int w4  = wq - 48 + 4 * q;           // may be <0 or >=W -> zeros
            pr0[it] = f32x4{0.f, 0.f, 0.f, 0.f};
            pr1[it] = f32x4{0.f, 0.f, 0.f, 0.f};
            if (w4 >= 0 && w4 + 3 < W_) {
                const float* g = rbase + (size_t)(c0 + 2 * rp) * HW_ + w4;
                pr0[it] = *(const f32x4*)g;
                pr1[it] = *(const f32x4*)(g + HW_);
            }
        }
    };

    // ---- pack prefetch regs -> LDS (vmcnt-waits exactly the loads used) ----
    auto WRITES = [&]() {
        #pragma unroll
        for (int it = 0; it < LITEMS; ++it) {
            int idx = tid + it * THREADS;
            if (idx < 32 * 20) {
                int rp  = idx / 20;
                int q   = idx - rp * 20;
                int chi = rp >> 2;
                int cb  = (rp & 3) << 2;
                #pragma unroll
                for (int j = 0; j < 4; ++j) {
                    int lw = 4 * q + j;
                    *(uint32_t*)(smem + lds_slotoff(lw, chi) + cb) =
                        pack2_bf16(pl0[it][j], pl1[it][j]);
                }
            }
        }
        #pragma unroll
        for (int it = 0; it < RITEMS; ++it) {
            int idx = tid + it * THREADS;
            int rp  = idx >> 5;
            int q   = idx & 31;
            int chi = rp >> 2;
            int cb  = (rp & 3) << 2;
            #pragma unroll
            for (int j = 0; j < 4; ++j) {
                int lw = 4 * q + j;
                *(uint32_t*)(smem + LBYTES + lds_slotoff(lw, chi) + cb) =
                    pack2_bf16(pr0[it][j], pr1[it][j]);
            }
        }
    };

    LOADS(0);
    for (int ch = 0; ch < NCHUNK; ++ch) {
        if (ch) lds_barrier();          // all waves done reading chunk ch-1
        WRITES();                       // stage chunk ch from prefetch regs
        if (ch + 1 < NCHUNK) LOADS((ch + 1) * KC);  // in flight across compute
        lds_barrier();                  // ds_writes visible; vmcnt NOT drained

        // ---- compute: 5 n-tiles, wave = jj; all reads ds_read_b128 ----
        #pragma unroll
        for (int ks = 0; ks < 2; ++ks) {
            const int chi = ks * 4 + l4;
            #pragma unroll
            for (int pi = 0; pi < 5; ++pi) {
                const int lwB = 16 * pi + l15;              // L row
                const int lwA = 16 * (pi + jj) + l15;       // R row
                bf16x8 bfrag = *(const bf16x8*)(smem + lds_slotoff(lwB, chi));
                bf16x8 afrag = *(const bf16x8*)(smem + LBYTES + lds_slotoff(lwA, chi));
                acc[pi] = __builtin_amdgcn_mfma_f32_16x16x32_bf16(afrag, bfrag, acc[pi], 0, 0, 0);
            }
        }
    }
    __syncthreads();   // epilogue overwrites LDS; no loads left in flight

    // ---- scatter accumulators -> LDS [D_][QW] f32 ----
    // D[m][n]: col tn = l15, row tm = 4*l4 + r.
    // w = wq + 16n + tn ; w' = wq - 48 + 16(n+jj) + tm ; d = 48 - 16*jj + tn - tm
    float* outs = (float*)smem;
    #pragma unroll
    for (int pi = 0; pi < 5; ++pi) {
        const int lw = 16 * pi + l15;   // 0..79, always in range
        #pragma unroll
        for (int r = 0; r < 4; ++r) {
            int tm = 4 * l4 + r;
            int d  = 48 - 16 * jj + l15 - tm;
            if (d >= 0 && d < D_) {
                outs[d * QW + lw] = acc[pi][r] * (1.f / 512.f);
            }
        }
    }
    __syncthreads();

    // ---- coalesced global store (guard w < W_ for last quarter) ----
    float* obase = out + (size_t)b * (D_ * HW_) + (size_t)h * W_ + wq;
    #pragma unroll
    for (int it = 0; it < (D_ * QW) / THREADS; ++it) {   // 15 iters
        int idx = it * THREADS + tid;
        int d   = idx / QW;
        int lw  = idx - d * QW;
        if (wq + lw < W_) {
            obase[(size_t)d * HW_ + lw] = outs[idx];
        }
    }
}

extern "C" void kernel_launch(void* const* d_in, const int* in_sizes, int n_in,
                              void* d_out, int out_size, void* d_ws, size_t ws_size,
                              hipStream_t stream) {
    const float* lf = (const float*)d_in[0];
    const float* rf = (const float*)d_in[1];
    float* out = (float*)d_out;
    dim3 grid(NQ, H_, B_);   // 1536 blocks
    psm_cost_volume<<<grid, THREADS, SMEM_BYTES, stream>>>(lf, rf, out);
}

// Round 8
// 122.646 us; speedup vs baseline: 1.5501x; 1.5501x over previous
//
#include <hip/hip_runtime.h>
#include <hip/hip_bf16.h>
#include <stdint.h>

// PSM cosine cost volume, MI355X (gfx950).
// out[b,d,h,w] = (1/C) * sum_c L[b,c,h,w] * R[b,c,h,w-d],  0 where w<d.
// Banded Gram matrix via bf16 MFMA 16x16x32.
//
// R8 = R7 tiling (256-thread blocks, quarter-row QW=80, 4 barrier teams/CU)
// with the two R7 confounders fixed:
//  - __launch_bounds__(256, 2): measured R5/R7, arg=4 hard-caps VGPR at 64 and
//    spills the 56-VGPR prefetch to scratch (+150MB traffic); arg=2 is safe.
//  - pack via v_cvt_pk_bf16_f32 (1 VALU op, RNE) instead of 6-op manual pack:
//    staging VALU was ~2/3 of all VALU cycles.
// Pipeline = R6 (register prefetch one chunk deep + lgkmcnt-only barriers;
// never drain vmcnt in the main loop).
//
// LDS layout per row lw (128B = 64 bf16 = KC channels), 16B slot s holds
// c in [8s',8s'+8) where s = s' ^ (lw&7) ^ ((lw>>4)&7):
//   (lw&7): read-side spread; ((lw>>4)&7): write-side spread, wave-uniform at
//   read (tile index) so fragment reads stay single ds_read_b128.
// Dword within slot = c-pair index (rp&3); bf16 pair = (even c, odd c).

#define B_ 4
#define C_ 512
#define H_ 96
#define W_ 312
#define D_ 48
#define HW_ (H_ * W_)      // 29952
#define CHW_ (C_ * HW_)

#define KC 64              // staged c per chunk
#define NCHUNK (C_ / KC)   // 8
#define NQ 4               // quarters per row
#define QW 80              // quarter width (last covers w=240..311, guarded)
#define LCOLS 80           // 5 N-tiles of 16
#define RCOLS 128          // [wq-48, wq+80): 8 M-tiles of 16 (pow2)
#define PITCH 128          // LDS row pitch bytes (64 bf16 = KC)
#define LBYTES (LCOLS * PITCH)          // 10240
#define RBYTES (RCOLS * PITCH)          // 16384
#define SMEM_BYTES (LBYTES + RBYTES)    // 26624 -> 4+ blocks/CU by LDS

#define THREADS 256
#define LITEMS 3           // ceil(32*20 / 256): it=2 only tid<128 (wave-uniform)
#define RITEMS 4           // 32*32 / 256 exactly

typedef __bf16 bf16x8 __attribute__((ext_vector_type(8)));
typedef float  f32x4  __attribute__((ext_vector_type(4)));

// RNE pack of two f32 -> packed 2xbf16 (a = low half = even c), 1 VALU op.
__device__ __forceinline__ uint32_t pack2_bf16(float a, float b) {
    uint32_t r;
    asm("v_cvt_pk_bf16_f32 %0, %1, %2" : "=v"(r) : "v"(a), "v"(b));
    return r;
}

// Byte offset of the 16B slot holding c-range [8*chi, 8*chi+8) of row lw.
__device__ __forceinline__ int lds_slotoff(int lw, int chi) {
    return lw * PITCH + ((chi ^ (lw & 7) ^ ((lw >> 4) & 7)) << 4);
}

// LDS-only drain + barrier (keeps global loads in flight across the barrier).
__device__ __forceinline__ void lds_barrier() {
    asm volatile("s_waitcnt lgkmcnt(0)" ::: "memory");
    __builtin_amdgcn_s_barrier();
}

__global__ __launch_bounds__(THREADS, 2)
void psm_cost_volume(const float* __restrict__ lf,
                     const float* __restrict__ rf,
                     float* __restrict__ out) {
    const int wq   = blockIdx.x * QW;   // 0,80,160,240
    const int h    = blockIdx.y;
    const int b    = blockIdx.z;
    const int tid  = threadIdx.x;
    const int lane = tid & 63;
    const int wave = tid >> 6;          // 4 waves
    const int l15  = lane & 15;
    const int l4   = lane >> 4;
    const int jj   = wave;              // A-tile offset 0..3

    extern __shared__ char smem[];
    // [0, LBYTES): L rows lw=0..79   (w  = wq + lw)
    // [LBYTES, +RBYTES): R rows lw=0..127 (w' = wq - 48 + lw)
    // epilogue reuses [0, D_*QW*4 = 15360) as f32 out staging

    const float* lbase = lf + (size_t)b * CHW_ + (size_t)h * W_;
    const float* rbase = rf + (size_t)b * CHW_ + (size_t)h * W_;

    f32x4 acc[5];
    #pragma unroll
    for (int i = 0; i < 5; ++i) acc[i] = f32x4{0.f, 0.f, 0.f, 0.f};

    // prefetch registers, one chunk deep: (3+4) items x 2 loads = 56 VGPR
    f32x4 pl0[LITEMS], pl1[LITEMS], pr0[RITEMS], pr1[RITEMS];

    // ---- issue loads for chunk starting at channel c0 into prefetch regs ----
    auto LOADS = [&](int c0) {
        #pragma unroll
        for (int it = 0; it < LITEMS; ++it) {
            int idx = tid + it * THREADS;        // q-fastest: coalesced runs
            if (idx < 32 * 20) {                 // it=2: tid<128, wave-uniform
                int rp = idx / 20;               // c-pair 0..31
                int q  = idx - rp * 20;          // float4 column 0..19
                int w4 = wq + 4 * q;
                pl0[it] = f32x4{0.f, 0.f, 0.f, 0.f};
                pl1[it] = f32x4{0.f, 0.f, 0.f, 0.f};
                if (w4 + 3 < W_) {               // quarter3 q>=18 OOB -> zeros
                    const float* g = lbase + (size_t)(c0 + 2 * rp) * HW_ + w4;
                    pl0[it] = *(const f32x4*)g;
                    pl1[it] = *(const f32x4*)(g + HW_);
                }
            }
        }
        #pragma unroll
        for (int it = 0; it < RITEMS; ++it) {
            int idx = tid + it * THREADS;
            int rp  = idx >> 5;                  // c-pair 0..31
            int q   = idx & 31;                  // float4 column 0..31
            int w4  = wq - 48 + 4 * q;           // may be <0 or >=W -> zeros
            pr0[it] = f32x4{0.f, 0.f, 0.f, 0.f};
            pr1[it] = f32x4{0.f, 0.f, 0.f, 0.f};
            if (w4 >= 0 && w4 + 3 < W_) {
                const float* g = rbase + (size_t)(c0 + 2 * rp) * HW_ + w4;
                pr0[it] = *(const f32x4*)g;
                pr1[it] = *(const f32x4*)(g + HW_);
            }
        }
    };

    // ---- pack prefetch regs -> LDS (vmcnt-waits exactly the loads used) ----
    auto WRITES = [&]() {
        #pragma unroll
        for (int it = 0; it < LITEMS; ++it) {
            int idx = tid + it * THREADS;
            if (idx < 32 * 20) {
                int rp  = idx / 20;
                int q   = idx - rp * 20;
                int chi = rp >> 2;
                int cb  = (rp & 3) << 2;
                #pragma unroll
                for (int j = 0; j < 4; ++j) {
                    int lw = 4 * q + j;
                    *(uint32_t*)(smem + lds_slotoff(lw, chi) + cb) =
                        pack2_bf16(pl0[it][j], pl1[it][j]);
                }
            }
        }
        #pragma unroll
        for (int it = 0; it < RITEMS; ++it) {
            int idx = tid + it * THREADS;
            int rp  = idx >> 5;
            int q   = idx & 31;
            int chi = rp >> 2;
            int cb  = (rp & 3) << 2;
            #pragma unroll
            for (int j = 0; j < 4; ++j) {
                int lw = 4 * q + j;
                *(uint32_t*)(smem + LBYTES + lds_slotoff(lw, chi) + cb) =
                    pack2_bf16(pr0[it][j], pr1[it][j]);
            }
        }
    };

    LOADS(0);
    for (int ch = 0; ch < NCHUNK; ++ch) {
        if (ch) lds_barrier();          // all waves done reading chunk ch-1
        WRITES();                       // stage chunk ch from prefetch regs
        if (ch + 1 < NCHUNK) LOADS((ch + 1) * KC);  // in flight across compute
        lds_barrier();                  // ds_writes visible; vmcnt NOT drained

        // ---- compute: 5 n-tiles, wave = jj; all reads ds_read_b128 ----
        #pragma unroll
        for (int ks = 0; ks < 2; ++ks) {
            const int chi = ks * 4 + l4;
            #pragma unroll
            for (int pi = 0; pi < 5; ++pi) {
                const int lwB = 16 * pi + l15;              // L row
                const int lwA = 16 * (pi + jj) + l15;       // R row
                bf16x8 bfrag = *(const bf16x8*)(smem + lds_slotoff(lwB, chi));
                bf16x8 afrag = *(const bf16x8*)(smem + LBYTES + lds_slotoff(lwA, chi));
                acc[pi] = __builtin_amdgcn_mfma_f32_16x16x32_bf16(afrag, bfrag, acc[pi], 0, 0, 0);
            }
        }
    }
    __syncthreads();   // epilogue overwrites LDS; no loads left in flight

    // ---- scatter accumulators -> LDS [D_][QW] f32 ----
    // D[m][n]: col tn = l15, row tm = 4*l4 + r.
    // w = wq + 16n + tn ; w' = wq - 48 + 16(n+jj) + tm ; d = 48 - 16*jj + tn - tm
    float* outs = (float*)smem;
    #pragma unroll
    for (int pi = 0; pi < 5; ++pi) {
        const int lw = 16 * pi + l15;   // 0..79, always in range
        #pragma unroll
        for (int r = 0; r < 4; ++r) {
            int tm = 4 * l4 + r;
            int d  = 48 - 16 * jj + l15 - tm;
            if (d >= 0 && d < D_) {
                outs[d * QW + lw] = acc[pi][r] * (1.f / 512.f);
            }
        }
    }
    __syncthreads();

    // ---- coalesced global store (guard w < W_ for last quarter) ----
    float* obase = out + (size_t)b * (D_ * HW_) + (size_t)h * W_ + wq;
    #pragma unroll
    for (int it = 0; it < (D_ * QW) / THREADS; ++it) {   // 15 iters
        int idx = it * THREADS + tid;
        int d   = idx / QW;
        int lw  = idx - d * QW;
        if (wq + lw < W_) {
            obase[(size_t)d * HW_ + lw] = outs[idx];
        }
    }
}

extern "C" void kernel_launch(void* const* d_in, const int* in_sizes, int n_in,
                              void* d_out, int out_size, void* d_ws, size_t ws_size,
                              hipStream_t stream) {
    const float* lf = (const float*)d_in[0];
    const float* rf = (const float*)d_in[1];
    float* out = (float*)d_out;
    dim3 grid(NQ, H_, B_);   // 1536 blocks
    psm_cost_volume<<<grid, THREADS, SMEM_BYTES, stream>>>(lf, rf, out);
}

// Round 9
// 111.950 us; speedup vs baseline: 1.6983x; 1.0955x over previous
//
#include <hip/hip_runtime.h>
#include <hip/hip_bf16.h>
#include <stdint.h>

// PSM cosine cost volume, MI355X (gfx950).
// out[b,d,h,w] = (1/C) * sum_c L[b,c,h,w] * R[b,c,h,w-d],  0 where w<d.
// Banded Gram matrix via bf16 MFMA 16x16x32.
//
// R9 = R8 (256-thread quarter-row tiles, reg-prefetch pipeline, cvt_pk pack)
//  + double-buffered LDS with ONE lgkmcnt-only barrier per chunk
//    (compute never vmcnt-stalls; barriers 16 -> 8)
//  + bijective XCD swizzle: each XCD owns 192 consecutive logical blocks =
//    all 4 w-quarters of 48 (b,h) rows -> R-halo sharing is XCD-L2-local.
// Measured R5/R7: __launch_bounds__ 2nd arg acts as min-BLOCKS-per-CU;
// arg>=4 caps VGPR at 64 and spills the 56-VGPR prefetch. Keep (256,2).
//
// LDS layout per row lw (128B = 64 bf16 = KC channels), 16B slot s holds
// c in [8s',8s'+8) where s = s' ^ (lw&7) ^ ((lw>>4)&7):
//   (lw&7): read-side spread; ((lw>>4)&7): write-side spread, wave-uniform at
//   read (tile index) so fragment reads stay single ds_read_b128.
// Dword within slot = c-pair index (rp&3); bf16 pair = (even c, odd c).

#define B_ 4
#define C_ 512
#define H_ 96
#define W_ 312
#define D_ 48
#define HW_ (H_ * W_)      // 29952
#define CHW_ (C_ * HW_)

#define KC 64              // staged c per chunk
#define NCHUNK (C_ / KC)   // 8
#define NQ 4               // quarters per row
#define QW 80              // quarter width (last covers w=240..311, guarded)
#define LCOLS 80           // 5 N-tiles of 16
#define RCOLS 128          // [wq-48, wq+80): 8 M-tiles of 16 (pow2)
#define PITCH 128          // LDS row pitch bytes (64 bf16 = KC)
#define LBYTES (LCOLS * PITCH)          // 10240
#define RBYTES (RCOLS * PITCH)          // 16384
#define SMEM_HALF (LBYTES + RBYTES)     // 26624
#define SMEM_BYTES (2 * SMEM_HALF)      // 53248 -> 3 blocks/CU by LDS

#define THREADS 256
#define NWG (NQ * H_ * B_)  // 1536 blocks, 1536 % 8 == 0
#define LITEMS 3            // ceil(32*20 / 256): it=2 only tid<128 (wave-uniform)
#define RITEMS 4            // 32*32 / 256 exactly

typedef __bf16 bf16x8 __attribute__((ext_vector_type(8)));
typedef float  f32x4  __attribute__((ext_vector_type(4)));

// RNE pack of two f32 -> packed 2xbf16 (a = low half = even c), 1 VALU op.
__device__ __forceinline__ uint32_t pack2_bf16(float a, float b) {
    uint32_t r;
    asm("v_cvt_pk_bf16_f32 %0, %1, %2" : "=v"(r) : "v"(a), "v"(b));
    return r;
}

// Byte offset of the 16B slot holding c-range [8*chi, 8*chi+8) of row lw.
__device__ __forceinline__ int lds_slotoff(int lw, int chi) {
    return lw * PITCH + ((chi ^ (lw & 7) ^ ((lw >> 4) & 7)) << 4);
}

// LDS-only drain + barrier (keeps global loads in flight across the barrier).
__device__ __forceinline__ void lds_barrier() {
    asm volatile("s_waitcnt lgkmcnt(0)" ::: "memory");
    __builtin_amdgcn_s_barrier();
}

__global__ __launch_bounds__(THREADS, 2)
void psm_cost_volume(const float* __restrict__ lf,
                     const float* __restrict__ rf,
                     float* __restrict__ out) {
    // Bijective XCD swizzle: xcd = lid%8 owns 192 consecutive logical ids.
    const int lid = blockIdx.x;
    const int swz = (lid & 7) * (NWG / 8) + (lid >> 3);
    const int q   = swz & 3;
    const int t   = swz >> 2;          // 0..383
    const int b   = t / H_;
    const int h   = t - b * H_;
    const int wq  = q * QW;            // 0,80,160,240

    const int tid  = threadIdx.x;
    const int lane = tid & 63;
    const int wave = tid >> 6;          // 4 waves
    const int l15  = lane & 15;
    const int l4   = lane >> 4;
    const int jj   = wave;              // A-tile offset 0..3

    extern __shared__ char smem[];
    // two halves, each: [0,LBYTES) L rows lw=0..79 (w = wq+lw),
    //                   [LBYTES,+RBYTES) R rows lw=0..127 (w' = wq-48+lw)
    // epilogue reuses [0, D_*QW*4 = 15360) as f32 out staging

    const float* lbase = lf + (size_t)b * CHW_ + (size_t)h * W_;
    const float* rbase = rf + (size_t)b * CHW_ + (size_t)h * W_;

    f32x4 acc[5];
    #pragma unroll
    for (int i = 0; i < 5; ++i) acc[i] = f32x4{0.f, 0.f, 0.f, 0.f};

    // prefetch registers, one chunk deep: (3+4) items x 2 loads = 56 VGPR
    f32x4 pl0[LITEMS], pl1[LITEMS], pr0[RITEMS], pr1[RITEMS];

    // ---- issue loads for chunk starting at channel c0 into prefetch regs ----
    auto LOADS = [&](int c0) {
        #pragma unroll
        for (int it = 0; it < LITEMS; ++it) {
            int idx = tid + it * THREADS;        // coalesced runs in w
            if (idx < 32 * 20) {                 // it=2: tid<128, wave-uniform
                int rp = idx / 20;               // c-pair 0..31
                int q4 = idx - rp * 20;          // float4 column 0..19
                int w4 = wq + 4 * q4;
                pl0[it] = f32x4{0.f, 0.f, 0.f, 0.f};
                pl1[it] = f32x4{0.f, 0.f, 0.f, 0.f};
                if (w4 + 3 < W_) {               // quarter3 tail OOB -> zeros
                    const float* g = lbase + (size_t)(c0 + 2 * rp) * HW_ + w4;
                    pl0[it] = *(const f32x4*)g;
                    pl1[it] = *(const f32x4*)(g + HW_);
                }
            }
        }
        #pragma unroll
        for (int it = 0; it < RITEMS; ++it) {
            int idx = tid + it * THREADS;
            int rp  = idx >> 5;                  // c-pair 0..31
            int q4  = idx & 31;                  // float4 column 0..31
            int w4  = wq - 48 + 4 * q4;          // may be <0 or >=W -> zeros
            pr0[it] = f32x4{0.f, 0.f, 0.f, 0.f};
            pr1[it] = f32x4{0.f, 0.f, 0.f, 0.f};
            if (w4 >= 0 && w4 + 3 < W_) {
                const float* g = rbase + (size_t)(c0 + 2 * rp) * HW_ + w4;
                pr0[it] = *(const f32x4*)g;
                pr1[it] = *(const f32x4*)(g + HW_);
            }
        }
    };

    // ---- pack prefetch regs -> LDS half `buf` (vmcnt-waits its loads) ----
    auto WRITES = [&](char* buf) {
        #pragma unroll
        for (int it = 0; it < LITEMS; ++it) {
            int idx = tid + it * THREADS;
            if (idx < 32 * 20) {
                int rp  = idx / 20;
                int q4  = idx - rp * 20;
                int chi = rp >> 2;
                int cb  = (rp & 3) << 2;
                #pragma unroll
                for (int j = 0; j < 4; ++j) {
                    int lw = 4 * q4 + j;
                    *(uint32_t*)(buf + lds_slotoff(lw, chi) + cb) =
                        pack2_bf16(pl0[it][j], pl1[it][j]);
                }
            }
        }
        #pragma unroll
        for (int it = 0; it < RITEMS; ++it) {
            int idx = tid + it * THREADS;
            int rp  = idx >> 5;
            int q4  = idx & 31;
            int chi = rp >> 2;
            int cb  = (rp & 3) << 2;
            #pragma unroll
            for (int j = 0; j < 4; ++j) {
                int lw = 4 * q4 + j;
                *(uint32_t*)(buf + LBYTES + lds_slotoff(lw, chi) + cb) =
                    pack2_bf16(pr0[it][j], pr1[it][j]);
            }
        }
    };

    // ---- prologue: fill buf0 with chunk 0, prefetch chunk 1 ----
    LOADS(0);
    WRITES(smem);                 // stalls full latency once (prologue only)
    LOADS(KC);
    lds_barrier();

    for (int ch = 0; ch < NCHUNK; ++ch) {
        const int cur = ch & 1;
        const char* rdbuf = smem + cur * SMEM_HALF;

        // ---- compute chunk ch: no vmcnt dependence, data barrier-guaranteed ----
        #pragma unroll
        for (int ks = 0; ks < 2; ++ks) {
            const int chi = ks * 4 + l4;
            #pragma unroll
            for (int pi = 0; pi < 5; ++pi) {
                const int lwB = 16 * pi + l15;              // L row
                const int lwA = 16 * (pi + jj) + l15;       // R row
                bf16x8 bfrag = *(const bf16x8*)(rdbuf + lds_slotoff(lwB, chi));
                bf16x8 afrag = *(const bf16x8*)(rdbuf + LBYTES + lds_slotoff(lwA, chi));
                acc[pi] = __builtin_amdgcn_mfma_f32_16x16x32_bf16(afrag, bfrag, acc[pi], 0, 0, 0);
            }
        }

        // ---- stage chunk ch+1 into the other half; prefetch chunk ch+2 ----
        if (ch + 1 < NCHUNK) {
            WRITES(smem + (cur ^ 1) * SMEM_HALF);  // waits chunk ch+1's loads
            if (ch + 2 < NCHUNK) LOADS((ch + 2) * KC);
            lds_barrier();          // reads of rdbuf + writes of other half done
        }
    }
    __syncthreads();   // epilogue overwrites LDS; nothing left in flight

    // ---- scatter accumulators -> LDS [D_][QW] f32 ----
    // D[m][n]: col tn = l15, row tm = 4*l4 + r.
    // w = wq + 16n + tn ; w' = wq - 48 + 16(n+jj) + tm ; d = 48 - 16*jj + tn - tm
    float* outs = (float*)smem;
    #pragma unroll
    for (int pi = 0; pi < 5; ++pi) {
        const int lw = 16 * pi + l15;   // 0..79
        #pragma unroll
        for (int r = 0; r < 4; ++r) {
            int tm = 4 * l4 + r;
            int d  = 48 - 16 * jj + l15 - tm;
            if (d >= 0 && d < D_) {
                outs[d * QW + lw] = acc[pi][r] * (1.f / 512.f);
            }
        }
    }
    __syncthreads();

    // ---- coalesced global store (guard w < W_ for last quarter) ----
    float* obase = out + (size_t)b * (D_ * HW_) + (size_t)h * W_ + wq;
    #pragma unroll
    for (int it = 0; it < (D_ * QW) / THREADS; ++it) {   // 15 iters
        int idx = it * THREADS + tid;
        int d   = idx / QW;
        int lw  = idx - d * QW;
        if (wq + lw < W_) {
            obase[(size_t)d * HW_ + lw] = outs[idx];
        }
    }
}

extern "C" void kernel_launch(void* const* d_in, const int* in_sizes, int n_in,
                              void* d_out, int out_size, void* d_ws, size_t ws_size,
                              hipStream_t stream) {
    const float* lf = (const float*)d_in[0];
    const float* rf = (const float*)d_in[1];
    float* out = (float*)d_out;
    psm_cost_volume<<<dim3(NWG), THREADS, SMEM_BYTES, stream>>>(lf, rf, out);
}